// Round 5
// baseline (242.768 us; speedup 1.0000x reference)
//
#include <hip/hip_runtime.h>
#include <hip/hip_bf16.h>
#include <stdint.h>

typedef __attribute__((ext_vector_type(8))) short s16x8;
typedef __attribute__((ext_vector_type(8))) unsigned short u16x8;
typedef __attribute__((ext_vector_type(4))) float f32x4;

#define SEQ 2048
#define LOG2E 1.44269504088896f

__device__ __forceinline__ unsigned short f2b(float x) {
  union { __hip_bfloat16 h; unsigned short u; } cv;
  cv.h = __float2bfloat16(x);
  return cv.u;
}

__device__ __forceinline__ float exp2fast(float x) {
  float r;
  asm("v_exp_f32 %0, %1" : "=v"(r) : "v"(x));
  return r;
}

__device__ __forceinline__ unsigned int cvtpk(float lo, float hi) {
  unsigned int r;
  asm("v_cvt_pk_bf16_f32 %0, %1, %2" : "=v"(r) : "v"(lo), "v"(hi));
  return r;
}

__device__ __forceinline__ void gload16(const void* g, void* l) {
  __builtin_amdgcn_global_load_lds(
      (const __attribute__((address_space(1))) void*)g,
      (__attribute__((address_space(3))) void*)l, 16, 0, 0);
}

__global__ void cvt_f32_bf16(const float* __restrict__ in,
                             __hip_bfloat16* __restrict__ out, int n4) {
  int i = blockIdx.x * blockDim.x + threadIdx.x;
  if (i >= n4) return;
  float4 v = reinterpret_cast<const float4*>(in)[i];
  ushort4 o;
  o.x = f2b(v.x); o.y = f2b(v.y); o.z = f2b(v.z); o.w = f2b(v.w);
  reinterpret_cast<ushort4*>(out)[i] = o;
}

// biasm[b][h][kv] = mask(b,kv) ? alibi(h,kv)*log2e : -1e30
__global__ void build_biasm(const float* __restrict__ abias,
                            const void* __restrict__ maskp,
                            float* __restrict__ biasm) {
  const int i = blockIdx.x * 256 + threadIdx.x;  // 65536 total
  const int b = i >> 15, h = (i >> 11) & 15, kv = i & 2047;
  const int* mi = (const int*)maskp;
  const unsigned char* mb = (const unsigned char*)maskp;
  const bool int_fmt = (mi[0] == 0 || mi[0] == 1);
  const bool ok = int_fmt ? (mi[b * SEQ + kv] != 0) : (mb[b * SEQ + kv] != 0);
  biasm[i] = ok ? abias[h * SEQ + kv] * LOG2E : -1e30f;
}

// C = A[M,K] * B^T (B is [N,K] row-major), + bias[N]
template <int MODE>
__global__ __launch_bounds__(256) void gemm_bt(
    const __hip_bfloat16* __restrict__ A, const __hip_bfloat16* __restrict__ B,
    const float* __restrict__ bias, void* __restrict__ Cout,
    __hip_bfloat16* __restrict__ Vt, int M, int N, int K) {
  __shared__ __align__(16) __hip_bfloat16 As[128 * 32];
  __shared__ __align__(16) __hip_bfloat16 Bs[128 * 32];
  const int tid = threadIdx.x;
  const int lane = tid & 63;
  const int w = tid >> 6;
  const int wr = w >> 1, wc = w & 1;
  const int rowg = blockIdx.x * 128;
  const int colg = blockIdx.y * 128;
  const int lr = lane & 15;
  const int lk = (lane >> 4) * 8;
  f32x4 acc[4][4];
#pragma unroll
  for (int m = 0; m < 4; ++m)
#pragma unroll
    for (int n = 0; n < 4; ++n) acc[m][n] = (f32x4){0.f, 0.f, 0.f, 0.f};
  for (int kt = 0; kt < K; kt += 32) {
#pragma unroll
    for (int r = 0; r < 2; ++r) {
      const int idx = r * 256 + tid;
      const int row = idx >> 2;
      const int ko = (idx & 3) * 8;
      gload16(A + (size_t)(rowg + row) * K + kt + ko, As + idx * 8);
      gload16(B + (size_t)(colg + row) * K + kt + ko, Bs + idx * 8);
    }
    __syncthreads();
    s16x8 af[4], bfr[4];
#pragma unroll
    for (int m = 0; m < 4; ++m)
      af[m] = *reinterpret_cast<const s16x8*>(As + (wr * 64 + m * 16 + lr) * 32 + lk);
#pragma unroll
    for (int n = 0; n < 4; ++n)
      bfr[n] = *reinterpret_cast<const s16x8*>(Bs + (wc * 64 + n * 16 + lr) * 32 + lk);
#pragma unroll
    for (int m = 0; m < 4; ++m)
#pragma unroll
      for (int n = 0; n < 4; ++n)
        acc[m][n] = __builtin_amdgcn_mfma_f32_16x16x32_bf16(af[m], bfr[n], acc[m][n], 0, 0, 0);
    __syncthreads();
  }
  const int r0l = (lane >> 4) * 4;
#pragma unroll
  for (int m = 0; m < 4; ++m) {
#pragma unroll
    for (int n = 0; n < 4; ++n) {
      const int col = colg + wc * 64 + n * 16 + lr;
      const int row0 = rowg + wr * 64 + m * 16 + r0l;
      const float bv = bias[col];
      if (MODE == 0) {
        if (col < 2048) {
          __hip_bfloat16* qkb = (__hip_bfloat16*)Cout;
#pragma unroll
          for (int j = 0; j < 4; ++j)
            qkb[(size_t)(row0 + j) * 2048 + col] = __float2bfloat16(acc[m][n][j] + bv);
        } else {
          const int c2 = col - 2048;
          const int bb = row0 >> 11;
          const int s0 = row0 & 2047;
          ushort4 pk;
          unsigned short* pp = (unsigned short*)&pk;
#pragma unroll
          for (int j = 0; j < 4; ++j) pp[j] = f2b(acc[m][n][j] + bv);
          *reinterpret_cast<ushort4*>(
              Vt + ((size_t)(bb * 16 + (c2 >> 6)) * 64 + (c2 & 63)) * 2048 + s0) = pk;
        }
      } else {
        float* o = (float*)Cout;
#pragma unroll
        for (int j = 0; j < 4; ++j)
          o[(size_t)(row0 + j) * N + col] = acc[m][n][j] + bv;
      }
    }
  }
}

// Barrier-free flash attention. Block = 4 waves, each wave independently owns
// 16 q-rows of the same 64-row q-tile. K/V read directly from global (L1/L2:
// per-(b,h) K+V = 512 KB, L2-fits; 4 waves share the kv stream via L1).
// Swapped QK^T (S'=mfma(K,Q)) -> per-lane-scalar softmax; PV as O^T=mfma(Vt,P)
// -> lane-private output column (no shuffles for rescale). P round-trips via
// wave-private 160B-stride LDS (bank-spread, no barrier). Per-CU balance:
// qt = (bx + bh) & 31 gives co-resident blocks qt = {r, r+8, r+16, r+24}.
__global__ __launch_bounds__(256, 4) void attn_fwd2(
    const __hip_bfloat16* __restrict__ qk, const __hip_bfloat16* __restrict__ Vt,
    const float* __restrict__ biasm, __hip_bfloat16* __restrict__ O) {
  __shared__ __align__(16) char Ps[4][2560];  // per-wave P: 16 rows x 160B
  const int tid = threadIdx.x;
  const int lane = tid & 63;
  const int w = tid >> 6;
  const int bh = blockIdx.y;
  const int b = bh >> 4, h = bh & 15;
  const int qt = (blockIdx.x + bh) & 31;
  const int q0 = qt * 64 + w * 16;
  const int nt = qt + 1;
  const int lr = lane & 15;
  const int g = lane >> 4;
  const float SCALE2 = 0.125f * LOG2E;
  // Q fragment (B-operand: col=q=lr, k=g*8..)
  const __hip_bfloat16* qptr = qk + (size_t)(b * SEQ + q0 + lr) * 2048 + h * 64 + g * 8;
  const s16x8 aq0 = *reinterpret_cast<const s16x8*>(qptr);
  const s16x8 aq1 = *reinterpret_cast<const s16x8*>(qptr + 32);
  const __hip_bfloat16* kbase = qk + (size_t)b * SEQ * 2048 + 1024 + h * 64 + g * 8;
  const __hip_bfloat16* vbase = Vt + ((size_t)bh * 64 + lr) * 2048 + g * 8;
  const float4* bmb = (const float4*)(biasm + (size_t)bh * 2048);
  const int q_abs = q0 + lr;
  char* pw = Ps[w];
  float m_r = -INFINITY, l_r = 0.f;
  f32x4 oa[4];
#pragma unroll
  for (int d = 0; d < 4; ++d) oa[d] = (f32x4){0.f, 0.f, 0.f, 0.f};

  for (int t = 0; t < nt; ++t) {
    const int kv0 = t * 64;
    // ---- S' = K Q^T : rows=kv, cols=q (K-frags direct from global) ----
    f32x4 sf[4];
#pragma unroll
    for (int n = 0; n < 4; ++n) {
      const __hip_bfloat16* kr = kbase + (size_t)(kv0 + n * 16 + lr) * 2048;
      const s16x8 a0 = *reinterpret_cast<const s16x8*>(kr);
      const s16x8 a1 = *reinterpret_cast<const s16x8*>(kr + 32);
      f32x4 z = (f32x4){0.f, 0.f, 0.f, 0.f};
      z = __builtin_amdgcn_mfma_f32_16x16x32_bf16(a0, aq0, z, 0, 0, 0);
      z = __builtin_amdgcn_mfma_f32_16x16x32_bf16(a1, aq1, z, 0, 0, 0);
      sf[n] = z;
    }
    // ---- scale + bias/padding (exp2 domain) ----
#pragma unroll
    for (int n = 0; n < 4; ++n) {
      const float4 bv = bmb[(kv0 >> 2) + n * 4 + g];
      sf[n][0] = fmaf(sf[n][0], SCALE2, bv.x);
      sf[n][1] = fmaf(sf[n][1], SCALE2, bv.y);
      sf[n][2] = fmaf(sf[n][2], SCALE2, bv.z);
      sf[n][3] = fmaf(sf[n][3], SCALE2, bv.w);
    }
    if (t == nt - 1) {  // causal only on diagonal tile
      const int kvb = kv0 + g * 4;
#pragma unroll
      for (int n = 0; n < 4; ++n)
#pragma unroll
        for (int j = 0; j < 4; ++j)
          if (kvb + n * 16 + j > q_abs) sf[n][j] = -1e30f;
    }
    // ---- online softmax (per-lane scalar state; col q is lane-private) ----
    float mx[4];
#pragma unroll
    for (int n = 0; n < 4; ++n)
      mx[n] = fmaxf(fmaxf(sf[n][0], sf[n][1]), fmaxf(sf[n][2], sf[n][3]));
    float tm = fmaxf(fmaxf(mx[0], mx[1]), fmaxf(mx[2], mx[3]));
    tm = fmaxf(tm, __shfl_xor(tm, 16));
    tm = fmaxf(tm, __shfl_xor(tm, 32));
    const float mn = fmaxf(m_r, tm);
    const float al = exp2fast(m_r - mn);
    m_r = mn;
    float ps[4];
#pragma unroll
    for (int n = 0; n < 4; ++n) {
#pragma unroll
      for (int j = 0; j < 4; ++j) sf[n][j] = exp2fast(sf[n][j] - mn);
      ps[n] = (sf[n][0] + sf[n][1]) + (sf[n][2] + sf[n][3]);
    }
    float rs = (ps[0] + ps[1]) + (ps[2] + ps[3]);
    rs += __shfl_xor(rs, 16);
    rs += __shfl_xor(rs, 32);
    l_r = l_r * al + rs;
#pragma unroll
    for (int d = 0; d < 4; ++d)
#pragma unroll
      for (int j = 0; j < 4; ++j) oa[d][j] *= al;
    // ---- P -> wave-private LDS (160B stride spreads banks), read B-frags ----
#pragma unroll
    for (int n = 0; n < 4; ++n) {
      uint2 pk;
      pk.x = cvtpk(sf[n][0], sf[n][1]);
      pk.y = cvtpk(sf[n][2], sf[n][3]);
      *reinterpret_cast<uint2*>(pw + lr * 160 + n * 32 + g * 8) = pk;
    }
    const s16x8 pa0 = *reinterpret_cast<const s16x8*>(pw + lr * 160 + g * 16);
    const s16x8 pa1 = *reinterpret_cast<const s16x8*>(pw + lr * 160 + 64 + g * 16);
    // ---- O^T += Vt P (A=Vt rows d, B=P cols q) ----
#pragma unroll
    for (int dt = 0; dt < 4; ++dt) {
      const __hip_bfloat16* vr = vbase + (size_t)(dt * 16) * 2048 + kv0;
      const s16x8 av0 = *reinterpret_cast<const s16x8*>(vr);
      const s16x8 av1 = *reinterpret_cast<const s16x8*>(vr + 32);
      oa[dt] = __builtin_amdgcn_mfma_f32_16x16x32_bf16(av0, pa0, oa[dt], 0, 0, 0);
      oa[dt] = __builtin_amdgcn_mfma_f32_16x16x32_bf16(av1, pa1, oa[dt], 0, 0, 0);
    }
  }
  // ---- epilogue: lane owns q = q_abs entirely ----
  const float li = 1.0f / l_r;
#pragma unroll
  for (int dt = 0; dt < 4; ++dt) {
    uint2 pk;
    pk.x = cvtpk(oa[dt][0] * li, oa[dt][1] * li);
    pk.y = cvtpk(oa[dt][2] * li, oa[dt][3] * li);
    *reinterpret_cast<uint2*>(&O[(size_t)(b * SEQ + q_abs) * 1024 + h * 64 + dt * 16 + g * 4]) = pk;
  }
}

extern "C" void kernel_launch(void* const* d_in, const int* in_sizes, int n_in,
                              void* d_out, int out_size, void* d_ws, size_t ws_size,
                              hipStream_t stream) {
  const float* x     = (const float*)d_in[0];
  const float* wqkv  = (const float*)d_in[1];
  const float* bqkv  = (const float*)d_in[2];
  const float* wout  = (const float*)d_in[3];
  const float* bout  = (const float*)d_in[4];
  const float* abias = (const float*)d_in[5];
  const void*  mask  = d_in[6];

  __hip_bfloat16* ws  = (__hip_bfloat16*)d_ws;
  __hip_bfloat16* xb  = ws;              // x bf16            [4096][1024]  (8 MB)
  __hip_bfloat16* wqb = ws + 4194304;    // Wqkv bf16         [3072][1024]  (6 MB)
  __hip_bfloat16* owb = ws + 7340032;    // out_w bf16        [1024][1024]  (2 MB)
  __hip_bfloat16* qkb = ws + 8388608;    // q|k bf16          [4096][2048]  (16 MB)
  __hip_bfloat16* vtb = ws + 16777216;   // V^T bf16          [2][16][64][2048] (8 MB)
  float*          bmf = (float*)(ws + 20971520);  // biasm [2][16][2048] f32 (256 KB)
  __hip_bfloat16* aob = xb;              // attn out bf16 overlays xb (dead after gemm1)

  cvt_f32_bf16<<<4096, 256, 0, stream>>>(x, xb, 1048576);
  cvt_f32_bf16<<<3072, 256, 0, stream>>>(wqkv, wqb, 786432);
  cvt_f32_bf16<<<1024, 256, 0, stream>>>(wout, owb, 262144);
  build_biasm<<<256, 256, 0, stream>>>(abias, mask, bmf);
  gemm_bt<0><<<dim3(32, 24), 256, 0, stream>>>(xb, wqb, bqkv, (void*)qkb, vtb,
                                               4096, 3072, 1024);
  attn_fwd2<<<dim3(32, 32), 256, 0, stream>>>(qkb, vtb, bmf, aob);
  gemm_bt<1><<<dim3(32, 8), 256, 0, stream>>>(aob, owb, bout, d_out,
                                              (__hip_bfloat16*)nullptr, 4096, 1024, 1024);
}

// Round 6
// 146.673 us; speedup vs baseline: 1.6552x; 1.6552x over previous
//
#include <hip/hip_runtime.h>
#include <hip/hip_bf16.h>
#include <stdint.h>

typedef __attribute__((ext_vector_type(8))) short s16x8;
typedef __attribute__((ext_vector_type(8))) unsigned short u16x8;
typedef __attribute__((ext_vector_type(4))) float f32x4;

#define SEQ 2048
#define LOG2E 1.44269504088896f

__device__ __forceinline__ unsigned short f2b(float x) {
  union { __hip_bfloat16 h; unsigned short u; } cv;
  cv.h = __float2bfloat16(x);
  return cv.u;
}

__device__ __forceinline__ float exp2fast(float x) {
  float r;
  asm("v_exp_f32 %0, %1" : "=v"(r) : "v"(x));
  return r;
}

__device__ __forceinline__ void gload16(const void* g, void* l) {
  __builtin_amdgcn_global_load_lds(
      (const __attribute__((address_space(1))) void*)g,
      (__attribute__((address_space(3))) void*)l, 16, 0, 0);
}

__global__ void cvt_f32_bf16(const float* __restrict__ in,
                             __hip_bfloat16* __restrict__ out, int n4) {
  int i = blockIdx.x * blockDim.x + threadIdx.x;
  if (i >= n4) return;
  float4 v = reinterpret_cast<const float4*>(in)[i];
  ushort4 o;
  o.x = f2b(v.x); o.y = f2b(v.y); o.z = f2b(v.z); o.w = f2b(v.w);
  reinterpret_cast<ushort4*>(out)[i] = o;
}

// biasm[b][h][kv] = mask(b,kv) ? alibi(h,kv)*log2e : -1e30
__global__ void build_biasm(const float* __restrict__ abias,
                            const void* __restrict__ maskp,
                            float* __restrict__ biasm) {
  const int i = blockIdx.x * 256 + threadIdx.x;  // 65536 total
  const int b = i >> 15, h = (i >> 11) & 15, kv = i & 2047;
  const int* mi = (const int*)maskp;
  const unsigned char* mb = (const unsigned char*)maskp;
  const bool int_fmt = (mi[0] == 0 || mi[0] == 1);
  const bool ok = int_fmt ? (mi[b * SEQ + kv] != 0) : (mb[b * SEQ + kv] != 0);
  biasm[i] = ok ? abias[h * SEQ + kv] * LOG2E : -1e30f;
}

// C = A[M,K] * B^T (B is [N,K] row-major), + bias[N]
template <int MODE>
__global__ __launch_bounds__(256) void gemm_bt(
    const __hip_bfloat16* __restrict__ A, const __hip_bfloat16* __restrict__ B,
    const float* __restrict__ bias, void* __restrict__ Cout,
    __hip_bfloat16* __restrict__ Vt, int M, int N, int K) {
  __shared__ __align__(16) __hip_bfloat16 As[128 * 32];
  __shared__ __align__(16) __hip_bfloat16 Bs[128 * 32];
  const int tid = threadIdx.x;
  const int lane = tid & 63;
  const int w = tid >> 6;
  const int wr = w >> 1, wc = w & 1;
  const int rowg = blockIdx.x * 128;
  const int colg = blockIdx.y * 128;
  const int lr = lane & 15;
  const int lk = (lane >> 4) * 8;
  f32x4 acc[4][4];
#pragma unroll
  for (int m = 0; m < 4; ++m)
#pragma unroll
    for (int n = 0; n < 4; ++n) acc[m][n] = (f32x4){0.f, 0.f, 0.f, 0.f};
  for (int kt = 0; kt < K; kt += 32) {
#pragma unroll
    for (int r = 0; r < 2; ++r) {
      const int idx = r * 256 + tid;
      const int row = idx >> 2;
      const int ko = (idx & 3) * 8;
      gload16(A + (size_t)(rowg + row) * K + kt + ko, As + idx * 8);
      gload16(B + (size_t)(colg + row) * K + kt + ko, Bs + idx * 8);
    }
    __syncthreads();
    s16x8 af[4], bfr[4];
#pragma unroll
    for (int m = 0; m < 4; ++m)
      af[m] = *reinterpret_cast<const s16x8*>(As + (wr * 64 + m * 16 + lr) * 32 + lk);
#pragma unroll
    for (int n = 0; n < 4; ++n)
      bfr[n] = *reinterpret_cast<const s16x8*>(Bs + (wc * 64 + n * 16 + lr) * 32 + lk);
#pragma unroll
    for (int m = 0; m < 4; ++m)
#pragma unroll
      for (int n = 0; n < 4; ++n)
        acc[m][n] = __builtin_amdgcn_mfma_f32_16x16x32_bf16(af[m], bfr[n], acc[m][n], 0, 0, 0);
    __syncthreads();
  }
  const int r0l = (lane >> 4) * 4;
#pragma unroll
  for (int m = 0; m < 4; ++m) {
#pragma unroll
    for (int n = 0; n < 4; ++n) {
      const int col = colg + wc * 64 + n * 16 + lr;
      const int row0 = rowg + wr * 64 + m * 16 + r0l;
      const float bv = bias[col];
      if (MODE == 0) {
        if (col < 2048) {
          __hip_bfloat16* qkb = (__hip_bfloat16*)Cout;
#pragma unroll
          for (int j = 0; j < 4; ++j)
            qkb[(size_t)(row0 + j) * 2048 + col] = __float2bfloat16(acc[m][n][j] + bv);
        } else {
          const int c2 = col - 2048;
          const int bb = row0 >> 11;
          const int s0 = row0 & 2047;
          ushort4 pk;
          unsigned short* pp = (unsigned short*)&pk;
#pragma unroll
          for (int j = 0; j < 4; ++j) pp[j] = f2b(acc[m][n][j] + bv);
          *reinterpret_cast<ushort4*>(
              Vt + ((size_t)(bb * 16 + (c2 >> 6)) * 64 + (c2 & 63)) * 2048 + s0) = pk;
        }
      } else {
        float* o = (float*)Cout;
#pragma unroll
        for (int j = 0; j < 4; ++j)
          o[(size_t)(row0 + j) * N + col] = acc[m][n][j] + bv;
      }
    }
  }
}

// XOR swizzle for [rows][128B] LDS tiles
__device__ __forceinline__ int swz(int row, int byteInRow) {
  return row * 128 + (byteInRow ^ ((row & 7) << 4));
}

// Swapped-operand attention tile (verified in r4): S' = mfma(K, Q) -> [kv, q].
// Lane owns ONE q column (q = lane&15): softmax state is a per-lane scalar.
__device__ __forceinline__ void attn_tile(
    const char* Ks, const char* Vs, char* pw, const float* Bm,
    s16x8 aq0, s16x8 aq1, int lane, int kv0, int q_abs, bool causal,
    float& m_r, float& l_r, f32x4* oa) {
  const int lr = lane & 15;
  const int g = lane >> 4;
  const int lkB = g * 16;
  const float SCALE2 = 0.125f * LOG2E;
  f32x4 sf[4];
#pragma unroll
  for (int n = 0; n < 4; ++n) {
    s16x8 ak0 = *reinterpret_cast<const s16x8*>(Ks + swz(n * 16 + lr, lkB));
    s16x8 ak1 = *reinterpret_cast<const s16x8*>(Ks + swz(n * 16 + lr, 64 + lkB));
    f32x4 z = (f32x4){0.f, 0.f, 0.f, 0.f};
    z = __builtin_amdgcn_mfma_f32_16x16x32_bf16(ak0, aq0, z, 0, 0, 0);
    z = __builtin_amdgcn_mfma_f32_16x16x32_bf16(ak1, aq1, z, 0, 0, 0);
    sf[n] = z;  // sf[n][j]: kv = kv0 + n*16 + g*4 + j, q = q_abs
  }
#pragma unroll
  for (int n = 0; n < 4; ++n) {
    f32x4 bv = *reinterpret_cast<const f32x4*>(Bm + n * 16 + g * 4);
#pragma unroll
    for (int j = 0; j < 4; ++j) sf[n][j] = fmaf(sf[n][j], SCALE2, bv[j]);
  }
  if (causal) {
    const int kvb = kv0 + g * 4;
#pragma unroll
    for (int n = 0; n < 4; ++n)
#pragma unroll
      for (int j = 0; j < 4; ++j)
        if (kvb + n * 16 + j > q_abs) sf[n][j] = -1e30f;
  }
  float mx[4];
#pragma unroll
  for (int n = 0; n < 4; ++n)
    mx[n] = fmaxf(fmaxf(sf[n][0], sf[n][1]), fmaxf(sf[n][2], sf[n][3]));
  float tm = fmaxf(fmaxf(mx[0], mx[1]), fmaxf(mx[2], mx[3]));
  tm = fmaxf(tm, __shfl_xor(tm, 16));
  tm = fmaxf(tm, __shfl_xor(tm, 32));
  const float mn = fmaxf(m_r, tm);
  const float al = exp2fast(m_r - mn);
  m_r = mn;
  float ps[4];
#pragma unroll
  for (int n = 0; n < 4; ++n) {
#pragma unroll
    for (int j = 0; j < 4; ++j) sf[n][j] = exp2fast(sf[n][j] - mn);
    ps[n] = (sf[n][0] + sf[n][1]) + (sf[n][2] + sf[n][3]);
  }
  float rs = (ps[0] + ps[1]) + (ps[2] + ps[3]);
  rs += __shfl_xor(rs, 16);
  rs += __shfl_xor(rs, 32);
  l_r = l_r * al + rs;
  float alj[4];
#pragma unroll
  for (int j = 0; j < 4; ++j) alj[j] = __shfl(al, g * 4 + j);
#pragma unroll
  for (int d = 0; d < 4; ++d)
#pragma unroll
    for (int j = 0; j < 4; ++j) oa[d][j] *= alj[j];
#pragma unroll
  for (int n = 0; n < 4; ++n) {
    union { ushort4 u; uint2 v; } pk;
    pk.u.x = f2b(sf[n][0]); pk.u.y = f2b(sf[n][1]);
    pk.u.z = f2b(sf[n][2]); pk.u.w = f2b(sf[n][3]);
    *reinterpret_cast<uint2*>(pw + lr * 128 + ((n * 32 + g * 8) ^ ((lr & 7) << 4))) = pk.v;
  }
  s16x8 pa0 = *reinterpret_cast<const s16x8*>(pw + swz(lr, lkB));
  s16x8 pa1 = *reinterpret_cast<const s16x8*>(pw + swz(lr, 64 + lkB));
#pragma unroll
  for (int d = 0; d < 4; ++d) {
    s16x8 bv0 = *reinterpret_cast<const s16x8*>(Vs + swz(d * 16 + lr, lkB));
    s16x8 bv1 = *reinterpret_cast<const s16x8*>(Vs + swz(d * 16 + lr, 64 + lkB));
    oa[d] = __builtin_amdgcn_mfma_f32_16x16x32_bf16(pa0, bv0, oa[d], 0, 0, 0);
    oa[d] = __builtin_amdgcn_mfma_f32_16x16x32_bf16(pa1, bv1, oa[d], 0, 0, 0);
  }
}

// kv-parity-split flash attention. Block = 8 waves on ONE 64-row q-tile.
// Waves 0-3 (z=0): even kv tiles; waves 4-7 (z=1): odd kv tiles. Each
// iteration stages BOTH parity tiles into separate buffers; every wave
// computes every iteration (no light-wave idle; loop length = ceil(nt/2)).
// Partials merge in LDS (r4-verified combine). qt=(bx+by)&31 spreads heavy
// blocks across CUs. 50 KB LDS -> 3 blocks/CU = 24 waves/CU.
__global__ __launch_bounds__(512) void attn_fwd3(
    const __hip_bfloat16* __restrict__ qk, const __hip_bfloat16* __restrict__ Vt,
    const float* __restrict__ biasm, __hip_bfloat16* __restrict__ O) {
  __shared__ __align__(16) char KV[2][2][64 * 128];  // [parity][K|V]
  __shared__ __align__(16) char Ps[8][16 * 128];     // per-wave P; merge area after
  __shared__ float Bm[2][64];
  __shared__ float mlArr[4][2][16];
  const int tid = threadIdx.x;
  const int lane = tid & 63;
  const int w = tid >> 6;
  const int wsub = w & 3;
  const int z = w >> 2;  // kv parity class
  const int bh = blockIdx.y;
  const int b = bh >> 4, h = bh & 15;
  const int qt = (blockIdx.x + bh) & 31;
  const int row0 = qt * 64 + wsub * 16;
  const int lr = lane & 15;
  const int g = lane >> 4;
  const int NTit = (qt >> 1) + 1;  // ceil((qt+1)/2)
  // Q fragment (B-operand: col=q=lr)
  const __hip_bfloat16* qbase = qk + (size_t)b * SEQ * 2048 + h * 64 + g * 8;
  const s16x8 aq0 = *reinterpret_cast<const s16x8*>(qbase + (size_t)(row0 + lr) * 2048);
  const s16x8 aq1 = *reinterpret_cast<const s16x8*>(qbase + (size_t)(row0 + lr) * 2048 + 32);
  const int q_abs = row0 + lr;
  float m_r = -INFINITY, l_r = 0.f;
  f32x4 oa[4];
#pragma unroll
  for (int d = 0; d < 4; ++d) oa[d] = (f32x4){0.f, 0.f, 0.f, 0.f};
  // staging: 512 threads x 16B = one 8KB tile per buffer
  const int srow = tid >> 3;  // 0..63
  const int c8 = tid & 7;
  const __hip_bfloat16* kbase = qk + (size_t)b * SEQ * 2048 + 1024 + h * 64 + c8 * 8;
  const __hip_bfloat16* vbase = Vt + ((size_t)bh * 64 + srow) * 2048 + c8 * 8;
  const float* bmb = biasm + (size_t)bh * 2048;
  u16x8 kpe, kpo, vpe, vpo;
  float bmv = 0.f;
#define ISSUE(T)                                                                 \
  {                                                                              \
    const int tE_ = 2 * (T);                                                     \
    const int tO_ = (2 * (T) + 1 <= qt) ? (2 * (T) + 1) : qt;                    \
    kpe = *reinterpret_cast<const u16x8*>(kbase + (size_t)(tE_ * 64 + srow) * 2048); \
    kpo = *reinterpret_cast<const u16x8*>(kbase + (size_t)(tO_ * 64 + srow) * 2048); \
    vpe = *reinterpret_cast<const u16x8*>(vbase + tE_ * 64);                     \
    vpo = *reinterpret_cast<const u16x8*>(vbase + tO_ * 64);                     \
    if (tid < 64) bmv = bmb[tE_ * 64 + tid];                                     \
    else if (tid < 128) bmv = bmb[tO_ * 64 + (tid - 64)];                        \
  }
  ISSUE(0);
  for (int t = 0; t < NTit; ++t) {
    __syncthreads();  // all waves done reading prev buffers
    *reinterpret_cast<u16x8*>(KV[0][0] + swz(srow, c8 * 16)) = kpe;
    *reinterpret_cast<u16x8*>(KV[1][0] + swz(srow, c8 * 16)) = kpo;
    *reinterpret_cast<u16x8*>(KV[0][1] + swz(srow, c8 * 16)) = vpe;
    *reinterpret_cast<u16x8*>(KV[1][1] + swz(srow, c8 * 16)) = vpo;
    if (tid < 64) Bm[0][tid] = bmv;
    else if (tid < 128) Bm[1][tid - 64] = bmv;
    __syncthreads();
    if (t + 1 < NTit) ISSUE(t + 1);  // latency hides under this tile's compute
    const int tz = 2 * t + z;
    if (tz <= qt)
      attn_tile(KV[z][0], KV[z][1], Ps[w], Bm[z], aq0, aq1, lane,
                tz * 64, q_abs, tz == qt, m_r, l_r, oa);
  }
#undef ISSUE
  // ---- merge partials: z=1 (wave w+4) into z=0 (wave w) ----
  __syncthreads();  // everyone done with Ps as P-buffer
  if (z == 1) {
    float* mo = (float*)(&Ps[0][0] + wsub * 4096);
#pragma unroll
    for (int d = 0; d < 4; ++d)
#pragma unroll
      for (int j = 0; j < 4; ++j)
        mo[(g * 4 + j) * 64 + d * 16 + lr] = oa[d][j];
    if (lane < 16) {
      mlArr[wsub][0][lr] = m_r;
      mlArr[wsub][1][lr] = l_r;
    }
  }
  __syncthreads();
  if (z == 0) {
    const float mB = mlArr[wsub][0][lr];
    const float lB = mlArr[wsub][1][lr];
    const float mS = fmaxf(m_r, mB);
    const float fA = exp2fast(m_r - mS);
    const float fB = exp2fast(mB - mS);
    const float linv = 1.0f / (l_r * fA + lB * fB);
    float fAj[4], fBj[4], lij[4];
#pragma unroll
    for (int j = 0; j < 4; ++j) {
      fAj[j] = __shfl(fA, g * 4 + j);
      fBj[j] = __shfl(fB, g * 4 + j);
      lij[j] = __shfl(linv, g * 4 + j);
    }
    const float* mo = (const float*)(&Ps[0][0] + wsub * 4096);
#pragma unroll
    for (int d = 0; d < 4; ++d)
#pragma unroll
      for (int j = 0; j < 4; ++j) {
        const float v =
            (oa[d][j] * fAj[j] + mo[(g * 4 + j) * 64 + d * 16 + lr] * fBj[j]) * lij[j];
        O[(size_t)(b * SEQ + row0 + g * 4 + j) * 1024 + h * 64 + d * 16 + lr] =
            __float2bfloat16(v);
      }
  }
}

extern "C" void kernel_launch(void* const* d_in, const int* in_sizes, int n_in,
                              void* d_out, int out_size, void* d_ws, size_t ws_size,
                              hipStream_t stream) {
  const float* x     = (const float*)d_in[0];
  const float* wqkv  = (const float*)d_in[1];
  const float* bqkv  = (const float*)d_in[2];
  const float* wout  = (const float*)d_in[3];
  const float* bout  = (const float*)d_in[4];
  const float* abias = (const float*)d_in[5];
  const void*  mask  = d_in[6];

  __hip_bfloat16* ws  = (__hip_bfloat16*)d_ws;
  __hip_bfloat16* xb  = ws;              // x bf16            [4096][1024]  (8 MB)
  __hip_bfloat16* wqb = ws + 4194304;    // Wqkv bf16         [3072][1024]  (6 MB)
  __hip_bfloat16* owb = ws + 7340032;    // out_w bf16        [1024][1024]  (2 MB)
  __hip_bfloat16* qkb = ws + 8388608;    // q|k bf16          [4096][2048]  (16 MB)
  __hip_bfloat16* vtb = ws + 16777216;   // V^T bf16          [2][16][64][2048] (8 MB)
  float*          bmf = (float*)(ws + 20971520);  // biasm [2][16][2048] f32 (256 KB)
  __hip_bfloat16* aob = xb;              // attn out bf16 overlays xb (dead after gemm1)

  cvt_f32_bf16<<<4096, 256, 0, stream>>>(x, xb, 1048576);
  cvt_f32_bf16<<<3072, 256, 0, stream>>>(wqkv, wqb, 786432);
  cvt_f32_bf16<<<1024, 256, 0, stream>>>(wout, owb, 262144);
  build_biasm<<<256, 256, 0, stream>>>(abias, mask, bmf);
  gemm_bt<0><<<dim3(32, 24), 256, 0, stream>>>(xb, wqb, bqkv, (void*)qkb, vtb,
                                               4096, 3072, 1024);
  attn_fwd3<<<dim3(32, 32), 512, 0, stream>>>(qkb, vtb, bmf, aob);
  gemm_bt<1><<<dim3(32, 8), 256, 0, stream>>>(aob, owb, bout, d_out,
                                              (__hip_bfloat16*)nullptr, 4096, 1024, 1024);
}

// Round 8
// 122.103 us; speedup vs baseline: 1.9882x; 1.2012x over previous
//
#include <hip/hip_runtime.h>
#include <hip/hip_bf16.h>
#include <stdint.h>

typedef __attribute__((ext_vector_type(8))) short s16x8;
typedef __attribute__((ext_vector_type(8))) unsigned short u16x8;
typedef __attribute__((ext_vector_type(4))) float f32x4;

#define SEQ 2048
#define LOG2E 1.44269504088896f

__device__ __forceinline__ unsigned short f2b(float x) {
  union { __hip_bfloat16 h; unsigned short u; } cv;
  cv.h = __float2bfloat16(x);
  return cv.u;
}

__device__ __forceinline__ float exp2fast(float x) {
  float r;
  asm("v_exp_f32 %0, %1" : "=v"(r) : "v"(x));
  return r;
}

__device__ __forceinline__ void gload16(const void* g, void* l) {
  __builtin_amdgcn_global_load_lds(
      (const __attribute__((address_space(1))) void*)g,
      (__attribute__((address_space(3))) void*)l, 16, 0, 0);
}

// fused bf16 conversion: x (1048576 float4) | Wqkv (786432) | out_w (262144)
// segment boundaries: 1048576, 1048576+786432=1835008, total 2097152
__global__ void cvt_all(const float* __restrict__ x, const float* __restrict__ wq,
                        const float* __restrict__ ow, __hip_bfloat16* __restrict__ xb,
                        __hip_bfloat16* __restrict__ wqb, __hip_bfloat16* __restrict__ owb) {
  const int i = blockIdx.x * 256 + threadIdx.x;  // 2097152 total
  const float* src;
  __hip_bfloat16* dst;
  int off;
  if (i < 1048576) { src = x; dst = xb; off = i; }
  else if (i < 1835008) { src = wq; dst = wqb; off = i - 1048576; }
  else { src = ow; dst = owb; off = i - 1835008; }
  float4 v = reinterpret_cast<const float4*>(src)[off];
  ushort4 o;
  o.x = f2b(v.x); o.y = f2b(v.y); o.z = f2b(v.z); o.w = f2b(v.w);
  reinterpret_cast<ushort4*>(dst)[off] = o;
}

// biasm[b][h][kv] = mask(b,kv) ? alibi(h,kv)*log2e : -1e30
__global__ void build_biasm(const float* __restrict__ abias,
                            const void* __restrict__ maskp,
                            float* __restrict__ biasm) {
  const int i = blockIdx.x * 256 + threadIdx.x;  // 65536 total
  const int b = i >> 15, h = (i >> 11) & 15, kv = i & 2047;
  const int* mi = (const int*)maskp;
  const unsigned char* mb = (const unsigned char*)maskp;
  const bool int_fmt = (mi[0] == 0 || mi[0] == 1);
  const bool ok = int_fmt ? (mi[b * SEQ + kv] != 0) : (mb[b * SEQ + kv] != 0);
  biasm[i] = ok ? abias[h * SEQ + kv] * LOG2E : -1e30f;
}

// C = A[M,K] * B^T (B is [N,K] row-major), + bias[N]. Tile BM x 128.
// MODE 0: bf16 out: col<2048 -> qk buffer [M][2048]; col>=2048 -> Vt[b][h][hd][s]
// MODE 1: f32 out [M][N]
template <int MODE, int BM>
__global__ __launch_bounds__(256) void gemm_bt(
    const __hip_bfloat16* __restrict__ A, const __hip_bfloat16* __restrict__ B,
    const float* __restrict__ bias, void* __restrict__ Cout,
    __hip_bfloat16* __restrict__ Vt, int M, int N, int K) {
  constexpr int MR = BM / 32;       // acc rows per wave
  __shared__ __align__(16) __hip_bfloat16 As[BM * 32];
  __shared__ __align__(16) __hip_bfloat16 Bs[128 * 32];
  const int tid = threadIdx.x;
  const int lane = tid & 63;
  const int w = tid >> 6;
  const int wr = w >> 1, wc = w & 1;
  const int rowg = blockIdx.x * BM;
  const int colg = blockIdx.y * 128;
  const int lr = lane & 15;
  const int lk = (lane >> 4) * 8;
  f32x4 acc[MR][4];
#pragma unroll
  for (int m = 0; m < MR; ++m)
#pragma unroll
    for (int n = 0; n < 4; ++n) acc[m][n] = (f32x4){0.f, 0.f, 0.f, 0.f};
  for (int kt = 0; kt < K; kt += 32) {
#pragma unroll
    for (int r = 0; r < BM / 64; ++r) {
      const int idx = r * 256 + tid;
      gload16(A + (size_t)(rowg + (idx >> 2)) * K + kt + (idx & 3) * 8, As + idx * 8);
    }
#pragma unroll
    for (int r = 0; r < 2; ++r) {
      const int idx = r * 256 + tid;
      gload16(B + (size_t)(colg + (idx >> 2)) * K + kt + (idx & 3) * 8, Bs + idx * 8);
    }
    __syncthreads();
    s16x8 af[MR], bfr[4];
#pragma unroll
    for (int m = 0; m < MR; ++m)
      af[m] = *reinterpret_cast<const s16x8*>(As + (wr * (BM / 2) + m * 16 + lr) * 32 + lk);
#pragma unroll
    for (int n = 0; n < 4; ++n)
      bfr[n] = *reinterpret_cast<const s16x8*>(Bs + (wc * 64 + n * 16 + lr) * 32 + lk);
#pragma unroll
    for (int m = 0; m < MR; ++m)
#pragma unroll
      for (int n = 0; n < 4; ++n)
        acc[m][n] = __builtin_amdgcn_mfma_f32_16x16x32_bf16(af[m], bfr[n], acc[m][n], 0, 0, 0);
    __syncthreads();
  }
  const int r0l = (lane >> 4) * 4;
#pragma unroll
  for (int m = 0; m < MR; ++m) {
#pragma unroll
    for (int n = 0; n < 4; ++n) {
      const int col = colg + wc * 64 + n * 16 + lr;
      const int row0 = rowg + wr * (BM / 2) + m * 16 + r0l;
      const float bv = bias[col];
      if (MODE == 0) {
        if (col < 2048) {
          __hip_bfloat16* qkb = (__hip_bfloat16*)Cout;
#pragma unroll
          for (int j = 0; j < 4; ++j)
            qkb[(size_t)(row0 + j) * 2048 + col] = __float2bfloat16(acc[m][n][j] + bv);
        } else {
          const int c2 = col - 2048;
          const int bb = row0 >> 11;
          const int s0 = row0 & 2047;
          ushort4 pk;
          unsigned short* pp = (unsigned short*)&pk;
#pragma unroll
          for (int j = 0; j < 4; ++j) pp[j] = f2b(acc[m][n][j] + bv);
          *reinterpret_cast<ushort4*>(
              Vt + ((size_t)(bb * 16 + (c2 >> 6)) * 64 + (c2 & 63)) * 2048 + s0) = pk;
        }
      } else {
        float* o = (float*)Cout;
#pragma unroll
        for (int j = 0; j < 4; ++j)
          o[(size_t)(row0 + j) * N + col] = acc[m][n][j] + bv;
      }
    }
  }
}

// XOR swizzle for [rows][128B] LDS tiles
__device__ __forceinline__ int swz(int row, int byteInRow) {
  return row * 128 + (byteInRow ^ ((row & 7) << 4));
}

// Swapped-operand attention tile (verified r4): S' = mfma(K, Q) -> [kv, q].
__device__ __forceinline__ void attn_tile(
    const char* Ks, const char* Vs, char* pw, const float* Bm,
    s16x8 aq0, s16x8 aq1, int lane, int kv0, int q_abs, bool causal,
    float& m_r, float& l_r, f32x4* oa) {
  const int lr = lane & 15;
  const int g = lane >> 4;
  const int lkB = g * 16;
  const float SCALE2 = 0.125f * LOG2E;
  f32x4 sf[4];
#pragma unroll
  for (int n = 0; n < 4; ++n) {
    s16x8 ak0 = *reinterpret_cast<const s16x8*>(Ks + swz(n * 16 + lr, lkB));
    s16x8 ak1 = *reinterpret_cast<const s16x8*>(Ks + swz(n * 16 + lr, 64 + lkB));
    f32x4 z = (f32x4){0.f, 0.f, 0.f, 0.f};
    z = __builtin_amdgcn_mfma_f32_16x16x32_bf16(ak0, aq0, z, 0, 0, 0);
    z = __builtin_amdgcn_mfma_f32_16x16x32_bf16(ak1, aq1, z, 0, 0, 0);
    sf[n] = z;
  }
#pragma unroll
  for (int n = 0; n < 4; ++n) {
    f32x4 bv = *reinterpret_cast<const f32x4*>(Bm + n * 16 + g * 4);
#pragma unroll
    for (int j = 0; j < 4; ++j) sf[n][j] = fmaf(sf[n][j], SCALE2, bv[j]);
  }
  if (causal) {
    const int kvb = kv0 + g * 4;
#pragma unroll
    for (int n = 0; n < 4; ++n)
#pragma unroll
      for (int j = 0; j < 4; ++j)
        if (kvb + n * 16 + j > q_abs) sf[n][j] = -1e30f;
  }
  float mx[4];
#pragma unroll
  for (int n = 0; n < 4; ++n)
    mx[n] = fmaxf(fmaxf(sf[n][0], sf[n][1]), fmaxf(sf[n][2], sf[n][3]));
  float tm = fmaxf(fmaxf(mx[0], mx[1]), fmaxf(mx[2], mx[3]));
  tm = fmaxf(tm, __shfl_xor(tm, 16));
  tm = fmaxf(tm, __shfl_xor(tm, 32));
  const float mn = fmaxf(m_r, tm);
  const float al = exp2fast(m_r - mn);
  m_r = mn;
  float ps[4];
#pragma unroll
  for (int n = 0; n < 4; ++n) {
#pragma unroll
    for (int j = 0; j < 4; ++j) sf[n][j] = exp2fast(sf[n][j] - mn);
    ps[n] = (sf[n][0] + sf[n][1]) + (sf[n][2] + sf[n][3]);
  }
  float rs = (ps[0] + ps[1]) + (ps[2] + ps[3]);
  rs += __shfl_xor(rs, 16);
  rs += __shfl_xor(rs, 32);
  l_r = l_r * al + rs;
  float alj[4];
#pragma unroll
  for (int j = 0; j < 4; ++j) alj[j] = __shfl(al, g * 4 + j);
#pragma unroll
  for (int d = 0; d < 4; ++d)
#pragma unroll
    for (int j = 0; j < 4; ++j) oa[d][j] *= alj[j];
#pragma unroll
  for (int n = 0; n < 4; ++n) {
    union { ushort4 u; uint2 v; } pk;
    pk.u.x = f2b(sf[n][0]); pk.u.y = f2b(sf[n][1]);
    pk.u.z = f2b(sf[n][2]); pk.u.w = f2b(sf[n][3]);
    *reinterpret_cast<uint2*>(pw + lr * 128 + ((n * 32 + g * 8) ^ ((lr & 7) << 4))) = pk.v;
  }
  s16x8 pa0 = *reinterpret_cast<const s16x8*>(pw + swz(lr, lkB));
  s16x8 pa1 = *reinterpret_cast<const s16x8*>(pw + swz(lr, 64 + lkB));
#pragma unroll
  for (int d = 0; d < 4; ++d) {
    s16x8 bv0 = *reinterpret_cast<const s16x8*>(Vs + swz(d * 16 + lr, lkB));
    s16x8 bv1 = *reinterpret_cast<const s16x8*>(Vs + swz(d * 16 + lr, 64 + lkB));
    oa[d] = __builtin_amdgcn_mfma_f32_16x16x32_bf16(pa0, bv0, oa[d], 0, 0, 0);
    oa[d] = __builtin_amdgcn_mfma_f32_16x16x32_bf16(pa1, bv1, oa[d], 0, 0, 0);
  }
}

// kv-parity-split flash attention (r6 structure) + heavy-first sorted 1-D grid.
// bid -> qt = 31 - bid/32 (heaviest blocks dispatch first -> refill packs the
// tail with light blocks), bh = bid & 31.
__global__ __launch_bounds__(512) void attn_fwd3(
    const __hip_bfloat16* __restrict__ qk, const __hip_bfloat16* __restrict__ Vt,
    const float* __restrict__ biasm, __hip_bfloat16* __restrict__ O) {
  __shared__ __align__(16) char KV[2][2][64 * 128];  // [parity][K|V]
  __shared__ __align__(16) char Ps[8][16 * 128];
  __shared__ float Bm[2][64];
  __shared__ float mlArr[4][2][16];
  const int tid = threadIdx.x;
  const int lane = tid & 63;
  const int w = tid >> 6;
  const int wsub = w & 3;
  const int z = w >> 2;
  const int bid = blockIdx.x;
  const int qt = 31 - (bid >> 5);
  const int bh = bid & 31;
  const int b = bh >> 4, h = bh & 15;
  const int row0 = qt * 64 + wsub * 16;
  const int lr = lane & 15;
  const int g = lane >> 4;
  const int NTit = (qt >> 1) + 1;
  const __hip_bfloat16* qbase = qk + (size_t)b * SEQ * 2048 + h * 64 + g * 8;
  const s16x8 aq0 = *reinterpret_cast<const s16x8*>(qbase + (size_t)(row0 + lr) * 2048);
  const s16x8 aq1 = *reinterpret_cast<const s16x8*>(qbase + (size_t)(row0 + lr) * 2048 + 32);
  const int q_abs = row0 + lr;
  float m_r = -INFINITY, l_r = 0.f;
  f32x4 oa[4];
#pragma unroll
  for (int d = 0; d < 4; ++d) oa[d] = (f32x4){0.f, 0.f, 0.f, 0.f};
  const int srow = tid >> 3;
  const int c8 = tid & 7;
  const __hip_bfloat16* kbase = qk + (size_t)b * SEQ * 2048 + 1024 + h * 64 + c8 * 8;
  const __hip_bfloat16* vbase = Vt + ((size_t)bh * 64 + srow) * 2048 + c8 * 8;
  const float* bmb = biasm + (size_t)bh * 2048;
  u16x8 kpe, kpo, vpe, vpo;
  float bmv = 0.f;
#define ISSUE(T)                                                                 \
  {                                                                              \
    const int tE_ = 2 * (T);                                                     \
    const int tO_ = (2 * (T) + 1 <= qt) ? (2 * (T) + 1) : qt;                    \
    kpe = *reinterpret_cast<const u16x8*>(kbase + (size_t)(tE_ * 64 + srow) * 2048); \
    kpo = *reinterpret_cast<const u16x8*>(kbase + (size_t)(tO_ * 64 + srow) * 2048); \
    vpe = *reinterpret_cast<const u16x8*>(vbase + tE_ * 64);                     \
    vpo = *reinterpret_cast<const u16x8*>(vbase + tO_ * 64);                     \
    if (tid < 64) bmv = bmb[tE_ * 64 + tid];                                     \
    else if (tid < 128) bmv = bmb[tO_ * 64 + (tid - 64)];                        \
  }
  ISSUE(0);
  for (int t = 0; t < NTit; ++t) {
    __syncthreads();
    *reinterpret_cast<u16x8*>(KV[0][0] + swz(srow, c8 * 16)) = kpe;
    *reinterpret_cast<u16x8*>(KV[1][0] + swz(srow, c8 * 16)) = kpo;
    *reinterpret_cast<u16x8*>(KV[0][1] + swz(srow, c8 * 16)) = vpe;
    *reinterpret_cast<u16x8*>(KV[1][1] + swz(srow, c8 * 16)) = vpo;
    if (tid < 64) Bm[0][tid] = bmv;
    else if (tid < 128) Bm[1][tid - 64] = bmv;
    __syncthreads();
    if (t + 1 < NTit) ISSUE(t + 1);
    const int tz = 2 * t + z;
    if (tz <= qt)
      attn_tile(KV[z][0], KV[z][1], Ps[w], Bm[z], aq0, aq1, lane,
                tz * 64, q_abs, tz == qt, m_r, l_r, oa);
  }
#undef ISSUE
  __syncthreads();
  if (z == 1) {
    float* mo = (float*)(&Ps[0][0] + wsub * 4096);
#pragma unroll
    for (int d = 0; d < 4; ++d)
#pragma unroll
      for (int j = 0; j < 4; ++j)
        mo[(g * 4 + j) * 64 + d * 16 + lr] = oa[d][j];
    if (lane < 16) {
      mlArr[wsub][0][lr] = m_r;
      mlArr[wsub][1][lr] = l_r;
    }
  }
  __syncthreads();
  if (z == 0) {
    const float mB = mlArr[wsub][0][lr];
    const float lB = mlArr[wsub][1][lr];
    const float mS = fmaxf(m_r, mB);
    const float fA = exp2fast(m_r - mS);
    const float fB = exp2fast(mB - mS);
    const float linv = 1.0f / (l_r * fA + lB * fB);
    float fAj[4], fBj[4], lij[4];
#pragma unroll
    for (int j = 0; j < 4; ++j) {
      fAj[j] = __shfl(fA, g * 4 + j);
      fBj[j] = __shfl(fB, g * 4 + j);
      lij[j] = __shfl(linv, g * 4 + j);
    }
    const float* mo = (const float*)(&Ps[0][0] + wsub * 4096);
#pragma unroll
    for (int d = 0; d < 4; ++d)
#pragma unroll
      for (int j = 0; j < 4; ++j) {
        const float v =
            (oa[d][j] * fAj[j] + mo[(g * 4 + j) * 64 + d * 16 + lr] * fBj[j]) * lij[j];
        O[(size_t)(b * SEQ + row0 + g * 4 + j) * 1024 + h * 64 + d * 16 + lr] =
            __float2bfloat16(v);
      }
  }
}

extern "C" void kernel_launch(void* const* d_in, const int* in_sizes, int n_in,
                              void* d_out, int out_size, void* d_ws, size_t ws_size,
                              hipStream_t stream) {
  const float* x     = (const float*)d_in[0];
  const float* wqkv  = (const float*)d_in[1];
  const float* bqkv  = (const float*)d_in[2];
  const float* wout  = (const float*)d_in[3];
  const float* bout  = (const float*)d_in[4];
  const float* abias = (const float*)d_in[5];
  const void*  mask  = d_in[6];

  __hip_bfloat16* ws  = (__hip_bfloat16*)d_ws;
  __hip_bfloat16* xb  = ws;              // x bf16            [4096][1024]  (8 MB)
  __hip_bfloat16* wqb = ws + 4194304;    // Wqkv bf16         [3072][1024]  (6 MB)
  __hip_bfloat16* owb = ws + 7340032;    // out_w bf16        [1024][1024]  (2 MB)
  __hip_bfloat16* qkb = ws + 8388608;    // q|k bf16          [4096][2048]  (16 MB)
  __hip_bfloat16* vtb = ws + 16777216;   // V^T bf16          [2][16][64][2048] (8 MB)
  float*          bmf = (float*)(ws + 20971520);  // biasm [2][16][2048] f32 (256 KB)
  __hip_bfloat16* aob = xb;              // attn out bf16 overlays xb (dead after gemm1)

  cvt_all<<<8192, 256, 0, stream>>>(x, wqkv, wout, xb, wqb, owb);
  build_biasm<<<256, 256, 0, stream>>>(abias, mask, bmf);
  gemm_bt<0, 128><<<dim3(32, 24), 256, 0, stream>>>(xb, wqb, bqkv, (void*)qkb, vtb,
                                                    4096, 3072, 1024);
  attn_fwd3<<<1024, 512, 0, stream>>>(qkb, vtb, bmf, aob);
  gemm_bt<1, 64><<<dim3(64, 8), 256, 0, stream>>>(aob, owb, bout, d_out,
                                                  (__hip_bfloat16*)nullptr, 4096, 1024, 1024);
}